// Round 5
// baseline (322.923 us; speedup 1.0000x reference)
//
#include <hip/hip_runtime.h>
#include <hip/hip_bf16.h>
#include <stdint.h>

#define D_MODEL 1024
#define N_HEADS 16
#define D_HEAD 64
#define BATCH 4
#define SEQ 2048
#define MTOT (BATCH * SEQ)   // 8192

typedef unsigned short u16;
typedef __attribute__((ext_vector_type(8))) short bf16x8;
typedef __attribute__((ext_vector_type(4))) float f32x4;

#define MFMA(a, b, c) __builtin_amdgcn_mfma_f32_16x16x32_bf16((a), (b), (c), 0, 0, 0)
#define LOG2E 1.4426950408889634f
#define SC (0.125f * LOG2E)   // folded into Wq at cvt time

// fp32 -> bf16 bits, round-to-nearest-even
static __device__ __forceinline__ u16 f2bf(float f) {
  unsigned u = __builtin_bit_cast(unsigned, f);
  u += 0x7fffu + ((u >> 16) & 1u);
  return (u16)(u >> 16);
}
// truncating (1 inst) — for p >= 0, error < 1 ulp
static __device__ __forceinline__ u16 f2bf_t(float f) {
  return (u16)(__builtin_bit_cast(unsigned, f) >> 16);
}

// pack 8 fp32 -> 8 bf16 (RNE, v_cvt_pk_bf16_f32)
static __device__ __forceinline__ bf16x8 pack8(float4 a, float4 b) {
  union { bf16x8 v; __hip_bfloat162 h[4]; } u;
  u.h[0] = __float22bfloat162_rn(make_float2(a.x, a.y));
  u.h[1] = __float22bfloat162_rn(make_float2(a.z, a.w));
  u.h[2] = __float22bfloat162_rn(make_float2(b.x, b.y));
  u.h[3] = __float22bfloat162_rn(make_float2(b.z, b.w));
  return u.v;
}

// async 16B global->LDS (dest = wave-uniform base + lane*16)
static __device__ __forceinline__ void gload_lds16(const void* g, void* l) {
  __builtin_amdgcn_global_load_lds(
      (const __attribute__((address_space(1))) void*)g,
      (__attribute__((address_space(3))) void*)l, 16, 0, 0);
}

// ---- weight convert: z==0 (Wq) gets the attention scale folded in ----
__global__ __launch_bounds__(256) void cvt4(const float* __restrict__ a,
                                            const float* __restrict__ b,
                                            const float* __restrict__ c,
                                            const float* __restrict__ d,
                                            u16* __restrict__ oa, u16* __restrict__ ob,
                                            u16* __restrict__ oc, u16* __restrict__ od) {
  const int z = blockIdx.y;
  const float* in = (z == 0) ? a : (z == 1) ? b : (z == 2) ? c : d;
  u16* out = (z == 0) ? oa : (z == 1) ? ob : (z == 2) ? oc : od;
  const float s = (z == 0) ? SC : 1.0f;
  int i = blockIdx.x * 256 + threadIdx.x;
  float4 v = ((const float4*)in)[i];
  ushort4 o;
  o.x = f2bf(v.x * s); o.y = f2bf(v.y * s); o.z = f2bf(v.z * s); o.w = f2bf(v.w * s);
  ((ushort4*)out)[i] = o;
}

// XOR chunk swizzle: logical 16B chunk cc of LDS row r lives at physical chunk
// cc^(r&7). Staging lane t (dest = physical chunk t&7 of row t>>3) fetches
// logical chunk (t&7)^(row&7). Fragment-read rows are ≡ lrow (mod 8) -> reader
// xor key is lrow&7. Spreads b128 reads over all 32 banks.

// ---- fused QKV projection: C = x @ W^T, x read as fp32 and converted in-kernel ----
// z=0 -> Q (scale pre-folded in Wqb); z=1 -> K; z=2 -> V TRANSPOSED [b][n][t]
__global__ __launch_bounds__(256, 4) void gemm_qkv(const float* __restrict__ xq,
                                                   const float* __restrict__ xk,
                                                   const float* __restrict__ xv,
                                                   const u16* __restrict__ Wqb,
                                                   const u16* __restrict__ Wkb,
                                                   const u16* __restrict__ Wvb,
                                                   u16* __restrict__ Qb,
                                                   u16* __restrict__ Kb,
                                                   u16* __restrict__ Vtg) {
  __shared__ u16 As[128 * 64];
  __shared__ u16 Bs[128 * 64];
  const int z = blockIdx.z;
  const float* A = (z == 0) ? xq : (z == 1) ? xk : xv;
  const u16* B = (z == 0) ? Wqb : (z == 1) ? Wkb : Wvb;

  const int t = threadIdx.x;
  const int lane = t & 63, wave = t >> 6;
  const int wm = wave & 1, wn = wave >> 1;
  const int lrow = lane & 15, quad = lane >> 4;
  const int m0 = blockIdx.x * 128, n0 = blockIdx.y * 128;
  const int srow = t >> 3;
  const int swcol = (((t & 7) ^ (srow & 7)) << 3);  // logical element col to fetch
  const int pchunk = (t & 7) * 8;                   // physical dest (u16 elements)
  const int rsw = lrow & 7;

  f32x4 acc[4][4];
#pragma unroll
  for (int i = 0; i < 4; i++)
#pragma unroll
    for (int j = 0; j < 4; j++) acc[i][j] = (f32x4){0.f, 0.f, 0.f, 0.f};

  for (int k0 = 0; k0 < 1024; k0 += 64) {
    // B: async DMA (bf16 weights)
#pragma unroll
    for (int r = 0; r < 4; ++r) {
      int rr = r * 32 + srow;
      gload_lds16(B + (size_t)(n0 + rr) * 1024 + k0 + swcol, Bs + rr * 64 + pchunk);
    }
    // A: fp32 load -> bf16 pack -> ds_write_b128 (same swizzled layout)
#pragma unroll
    for (int r = 0; r < 4; ++r) {
      int rr = r * 32 + srow;
      const float4* src = (const float4*)(A + (size_t)(m0 + rr) * 1024 + k0 + swcol);
      float4 fa = src[0], fb = src[1];
      *(bf16x8*)(As + rr * 64 + pchunk) = pack8(fa, fb);
    }
    __syncthreads();  // drains DMA vmcnt + ds_write lgkmcnt, then barrier
#pragma unroll
    for (int ks = 0; ks < 2; ++ks) {
      const int cx = ((ks * 4 + quad) ^ rsw) << 3;
      bf16x8 a[4], b[4];
#pragma unroll
      for (int i = 0; i < 4; i++)
        a[i] = *(const bf16x8*)(As + (wm * 64 + i * 16 + lrow) * 64 + cx);
#pragma unroll
      for (int j = 0; j < 4; j++)
        b[j] = *(const bf16x8*)(Bs + (wn * 64 + j * 16 + lrow) * 64 + cx);
#pragma unroll
      for (int i = 0; i < 4; i++)
#pragma unroll
        for (int j = 0; j < 4; j++) acc[i][j] = MFMA(a[i], b[j], acc[i][j]);
    }
    __syncthreads();
  }
  // C/D: col = lane&15 (n), row = quad*4 + reg (m)
  if (z == 2) {
    const int b = m0 >> 11;
    const int t0 = (m0 & 2047);
#pragma unroll
    for (int i = 0; i < 4; i++) {
      const int trow = t0 + wm * 64 + i * 16 + quad * 4;
#pragma unroll
      for (int j = 0; j < 4; j++) {
        const int n = n0 + wn * 64 + j * 16 + lrow;
        ushort4 pk;
        pk.x = f2bf(acc[i][j][0]); pk.y = f2bf(acc[i][j][1]);
        pk.z = f2bf(acc[i][j][2]); pk.w = f2bf(acc[i][j][3]);
        *(ushort4*)(Vtg + (size_t)b * D_MODEL * SEQ + (size_t)n * SEQ + trow) = pk;
      }
    }
  } else {
    u16* C = z ? Kb : Qb;
#pragma unroll
    for (int i = 0; i < 4; i++) {
      const int mr = m0 + wm * 64 + i * 16 + quad * 4;
#pragma unroll
      for (int j = 0; j < 4; j++) {
        const int n = n0 + wn * 64 + j * 16 + lrow;
#pragma unroll
        for (int r = 0; r < 4; r++) C[(size_t)(mr + r) * 1024 + n] = f2bf(acc[i][j][r]);
      }
    }
  }
}

// ---- output projection: 128x64 tiles for occupancy (1024 blocks, 24 KB LDS) ----
__global__ __launch_bounds__(256) void gemm_o(const u16* __restrict__ A,
                                              const u16* __restrict__ B,
                                              float* __restrict__ C) {
  __shared__ u16 As[128 * 64];  // 16 KB
  __shared__ u16 Bs[64 * 64];   // 8 KB
  const int t = threadIdx.x;
  const int lane = t & 63, wave = t >> 6;
  const int lrow = lane & 15, quad = lane >> 4;
  const int m0 = blockIdx.x * 128, n0 = blockIdx.y * 64;
  const int srow = t >> 3;
  const int swcol = (((t & 7) ^ (srow & 7)) << 3);
  const int pchunk = (t & 7) * 8;
  const int rsw = lrow & 7;

  f32x4 acc[2][4];
#pragma unroll
  for (int i = 0; i < 2; i++)
#pragma unroll
    for (int j = 0; j < 4; j++) acc[i][j] = (f32x4){0.f, 0.f, 0.f, 0.f};

  for (int k0 = 0; k0 < 1024; k0 += 64) {
#pragma unroll
    for (int r = 0; r < 4; ++r) {
      int rr = r * 32 + srow;
      gload_lds16(A + (size_t)(m0 + rr) * 1024 + k0 + swcol, As + rr * 64 + pchunk);
    }
#pragma unroll
    for (int r = 0; r < 2; ++r) {
      int rr = r * 32 + srow;
      gload_lds16(B + (size_t)(n0 + rr) * 1024 + k0 + swcol, Bs + rr * 64 + pchunk);
    }
    __syncthreads();
#pragma unroll
    for (int ks = 0; ks < 2; ++ks) {
      const int cx = ((ks * 4 + quad) ^ rsw) << 3;
      bf16x8 a[2], b[4];
#pragma unroll
      for (int i = 0; i < 2; i++)
        a[i] = *(const bf16x8*)(As + (wave * 32 + i * 16 + lrow) * 64 + cx);
#pragma unroll
      for (int j = 0; j < 4; j++)
        b[j] = *(const bf16x8*)(Bs + (j * 16 + lrow) * 64 + cx);
#pragma unroll
      for (int i = 0; i < 2; i++)
#pragma unroll
        for (int j = 0; j < 4; j++) acc[i][j] = MFMA(a[i], b[j], acc[i][j]);
    }
    __syncthreads();
  }
#pragma unroll
  for (int i = 0; i < 2; i++) {
    const int mr = m0 + wave * 32 + i * 16 + quad * 4;
#pragma unroll
    for (int j = 0; j < 4; j++) {
      const int n = n0 + j * 16 + lrow;
#pragma unroll
      for (int r = 0; r < 4; r++) C[(size_t)(mr + r) * 1024 + n] = acc[i][j][r];
    }
  }
}

// ---- causal flash attention (unchanged from round 4) ----
// 128-row Q tiles, 4 waves x 32 rows. grid (64, 8): x = b*16+h, y pairs qt=y
// with 15-y (34 k-tiles each). Q frags in registers; QPs LDS reused for P.
// S^T = MFMA(K,Q) -> P written as ushort4, read as PV A-operand.
// Fixed-base softmax (scale folded into Wq); l = P*ones via MFMA.
__global__ __launch_bounds__(256) void attn_causal(const u16* __restrict__ Qb,
                                                   const u16* __restrict__ Kb,
                                                   const u16* __restrict__ Vtg,
                                                   u16* __restrict__ Ob) {
  __shared__ u16 QPs[128 * 64];  // 16 KB: Q staging, then P
  __shared__ u16 Ks[64 * 64];    // 8 KB
  __shared__ u16 Vs[64 * 64];    // 8 KB  V^T tile [d][j]

  const int t = threadIdx.x;
  const int lane = t & 63, wave = t >> 6;
  const int lrow = lane & 15, quad = lane >> 4;
  const int wb = wave * 32;
  const int bh = blockIdx.x;
  const int b = bh >> 4, h = bh & 15;
  const int col0 = h * 64;
  const size_t rowbase = (size_t)b * SEQ;
  const size_t vbase = (size_t)b * (size_t)D_MODEL * SEQ;
  const int srow = t >> 3;
  const int swcol = (((t & 7) ^ (srow & 7)) << 3);
  const int pchunk = (t & 7) * 8;
  const int rsw = lrow & 7;

  bf16x8 bOnes;
  {
    const short ov = (lrow == 0) ? (short)0x3F80 : (short)0;
#pragma unroll
    for (int e = 0; e < 8; ++e) bOnes[e] = ov;
  }

  for (int part = 0; part < 2; ++part) {
    const int qt = part ? (15 - (int)blockIdx.y) : (int)blockIdx.y;
    const int qrow0 = qt * 128;

#pragma unroll
    for (int r = 0; r < 4; ++r) {
      int rr = r * 32 + srow;
      gload_lds16(Qb + (rowbase + qrow0 + rr) * D_MODEL + col0 + swcol,
                  QPs + rr * 64 + pchunk);
    }

    bf16x8 bQ[2][2];
    f32x4 oacc[2][4];
    f32x4 lacc[2];
#pragma unroll
    for (int mf = 0; mf < 2; mf++) {
#pragma unroll
      for (int df = 0; df < 4; df++) oacc[mf][df] = (f32x4){0.f, 0.f, 0.f, 0.f};
      lacc[mf] = (f32x4){0.f, 0.f, 0.f, 0.f};
    }

    const int nkt = 2 * qt + 2;
    for (int kt = 0; kt < nkt; ++kt) {
      const int j0 = kt * 64;
      __syncthreads();
#pragma unroll
      for (int r = 0; r < 2; ++r) {
        int rr = r * 32 + srow;
        gload_lds16(Kb + (rowbase + j0 + rr) * D_MODEL + col0 + swcol,
                    Ks + rr * 64 + pchunk);
        gload_lds16(Vtg + vbase + (size_t)(col0 + rr) * SEQ + j0 + swcol,
                    Vs + rr * 64 + pchunk);
      }
      __syncthreads();

      if (kt == 0) {
#pragma unroll
        for (int mf = 0; mf < 2; ++mf)
#pragma unroll
          for (int ks = 0; ks < 2; ++ks)
            bQ[mf][ks] = *(const bf16x8*)(QPs + (wb + mf * 16 + lrow) * 64 +
                                          (((ks * 4 + quad) ^ rsw) << 3));
      }

      const bool diag = (kt >= 2 * qt);
#pragma unroll
      for (int mf = 0; mf < 2; ++mf) {
        f32x4 st[4];
#pragma unroll
        for (int jf = 0; jf < 4; jf++) st[jf] = (f32x4){0.f, 0.f, 0.f, 0.f};
#pragma unroll
        for (int ks = 0; ks < 2; ++ks) {
          const int cx = ((ks * 4 + quad) ^ rsw) << 3;
#pragma unroll
          for (int jf = 0; jf < 4; jf++) {
            bf16x8 aK = *(const bf16x8*)(Ks + (jf * 16 + lrow) * 64 + cx);
            st[jf] = MFMA(aK, bQ[mf][ks], st[jf]);
          }
        }
        const int m = wb + mf * 16 + lrow;
        const int gm = qrow0 + m;
#pragma unroll
        for (int jf = 0; jf < 4; jf++) {
          ushort4 pk;
#pragma unroll
          for (int r = 0; r < 4; r++) {
            float p = __builtin_amdgcn_exp2f(st[jf][r]);
            const int gj = j0 + jf * 16 + quad * 4 + r;
            if (diag && gj > gm) p = 0.f;
            ((u16*)&pk)[r] = f2bf_t(p);
          }
          const int j = jf * 16 + quad * 4;
          *(ushort4*)(QPs + m * 64 + ((((j >> 3) ^ (m & 7)) << 3) | (j & 7))) = pk;
        }
      }

#pragma unroll
      for (int ks = 0; ks < 2; ++ks) {
        const int cx = ((ks * 4 + quad) ^ rsw) << 3;
        bf16x8 aP[2];
#pragma unroll
        for (int mf = 0; mf < 2; ++mf)
          aP[mf] = *(const bf16x8*)(QPs + (wb + mf * 16 + lrow) * 64 + cx);
        lacc[0] = MFMA(aP[0], bOnes, lacc[0]);
        lacc[1] = MFMA(aP[1], bOnes, lacc[1]);
#pragma unroll
        for (int df = 0; df < 4; df++) {
          bf16x8 bV = *(const bf16x8*)(Vs + (df * 16 + lrow) * 64 + cx);
          oacc[0][df] = MFMA(aP[0], bV, oacc[0][df]);
          oacc[1][df] = MFMA(aP[1], bV, oacc[1][df]);
        }
      }
    }
    __syncthreads();

    float linv[2][4];
#pragma unroll
    for (int mf = 0; mf < 2; mf++)
#pragma unroll
      for (int r = 0; r < 4; r++)
        linv[mf][r] = 1.0f / __shfl(lacc[mf][r], lane & 48);

#pragma unroll
    for (int mf = 0; mf < 2; mf++)
#pragma unroll
      for (int r = 0; r < 4; r++) {
        u16* orow = Ob + (rowbase + qrow0 + wb + mf * 16 + quad * 4 + r) * D_MODEL + col0;
#pragma unroll
        for (int df = 0; df < 4; df++)
          orow[df * 16 + lrow] = f2bf(oacc[mf][df][r] * linv[mf][r]);
      }
  }
}

extern "C" void kernel_launch(void* const* d_in, const int* in_sizes, int n_in,
                              void* d_out, int out_size, void* d_ws, size_t ws_size,
                              hipStream_t stream) {
  const float* q  = (const float*)d_in[0];
  const float* k  = (const float*)d_in[1];
  const float* v  = (const float*)d_in[2];
  // d_in[3] = mask — strict-upper-triangle causal; handled analytically
  const float* Wq = (const float*)d_in[4];
  const float* Wk = (const float*)d_in[5];
  const float* Wv = (const float*)d_in[6];
  const float* Wo = (const float*)d_in[7];
  float* out = (float*)d_out;

  char* ws = (char*)d_ws;
  const size_t MB = 1 << 20;
  u16* Oatt = (u16*)(ws);             // 16 MiB
  u16* Qb   = (u16*)(ws + 16 * MB);   // 16 MiB
  u16* Kb   = (u16*)(ws + 32 * MB);   // 16 MiB
  u16* Vtg  = (u16*)(ws + 48 * MB);   // 16 MiB
  u16* Wqb  = (u16*)(ws + 64 * MB);   // 2 MiB each
  u16* Wkb  = (u16*)(ws + 66 * MB);
  u16* Wvb  = (u16*)(ws + 68 * MB);
  u16* Wob  = (u16*)(ws + 70 * MB);   // total 72 MiB

  const dim3 cb(256);
  cvt4<<<dim3(D_MODEL * D_MODEL / 4 / 256, 4), cb, 0, stream>>>(Wq, Wk, Wv, Wo,
                                                                Wqb, Wkb, Wvb, Wob);
  gemm_qkv<<<dim3(64, 8, 3), cb, 0, stream>>>(q, k, v, Wqb, Wkb, Wvb, Qb, Kb, Vtg);
  attn_causal<<<dim3(64, 8), cb, 0, stream>>>(Qb, Kb, Vtg, Oatt);
  gemm_o<<<dim3(64, 16), cb, 0, stream>>>(Oatt, Wob, out);
}